// Round 12
// baseline (197.613 us; speedup 1.0000x reference)
//
#include <hip/hip_runtime.h>
#include <hip/hip_cooperative_groups.h>
namespace cg = cooperative_groups;

#define NUM_GRAPHS 512
#define N_NODES 100000
#define N_EDGES 1600000
#define D_NODE 128
#define D_EDGE 32
#define D_OUT 64

#define NBLK 512                 // prep blocks = graphs (phase 2 maps block b -> graph b)
#define EPB (N_EDGES / NBLK)     // 3125 edges per block (exact)
#define NREM (EPB - 3072)        // 53 remainder edges per block
#define GCAP 5120                // per-graph id cap: deg mean 3125, sigma ~228 -> 8.7 sigma
#define NCHUNK ((N_NODES + NBLK - 1) / NBLK)   // 196 nodes per block

// ---------------- kernel 1: cooperative prep: count -> (scan + node-sum) -> place -----
// Edge graph-ids live in REGISTERS across all three phases (no eg buffer, no rereads).
__global__ __launch_bounds__(512) void prep_kernel(const int* __restrict__ col,
                                                   const int* __restrict__ batch,
                                                   const float* __restrict__ x,
                                                   int* __restrict__ cntT,
                                                   int* __restrict__ pos,
                                                   int* __restrict__ totals,
                                                   int* __restrict__ bucket,
                                                   float* __restrict__ node_agg) {
    cg::grid_group grid = cg::this_grid();
    const int t = threadIdx.x, b = blockIdx.x;
    __shared__ int cur[NUM_GRAPHS];
    __shared__ float4 red[512];
    __shared__ int wtot[8], wbase[8];

    // ---- phase 1: count into LDS histogram; keep gg[] in registers; zero node_agg ----
    cur[t] = 0;
    __syncthreads();
    const int base = b * EPB;
    int c[6];
    #pragma unroll
    for (int r = 0; r < 6; ++r) c[r] = col[base + r * 512 + t];    // 6 coalesced loads in flight
    const int crem = (t < NREM) ? col[base + 3072 + t] : 0;
    int gg[6];
    #pragma unroll
    for (int r = 0; r < 6; ++r) gg[r] = batch[c[r]];               // 7 independent gathers
    const int grem = (t < NREM) ? batch[crem] : -1;
    #pragma unroll
    for (int r = 0; r < 6; ++r) atomicAdd(&cur[gg[r]], 1);
    if (grem >= 0) atomicAdd(&cur[grem], 1);
    if (t < D_NODE) node_agg[b * D_NODE + t] = 0.f;                // block b zeros graph b's row
    __syncthreads();
    cntT[t * NBLK + b] = cur[t];                                   // [g][b] scattered 4B -> L2
    grid.sync();

    // ---- phase 2a: per-graph scan over blocks (block b = graph b, wave-shuffle) ------
    {
        const int n = cntT[b * NBLK + t];                          // coalesced row read
        const int lane = t & 63, w = t >> 6;
        int v = n;
        #pragma unroll
        for (int off = 1; off < 64; off <<= 1) {
            const int u = __shfl_up(v, off, 64);
            if (lane >= off) v += u;
        }
        if (lane == 63) wtot[w] = v;
        __syncthreads();
        if (t == 0) {
            int s = 0;
            #pragma unroll
            for (int i = 0; i < 8; ++i) { wbase[i] = s; s += wtot[i]; }
        }
        __syncthreads();
        pos[t * NUM_GRAPHS + b] = b * GCAP + wbase[w] + v - n;     // [blk][g] scattered -> L2
        if (t == 511) totals[b] = wbase[7] + v;
    }

    // ---- phase 2b: node aggregation (overlaps scan; batch sorted -> <=3 segments) ----
    {
        const float4* x4 = reinterpret_cast<const float4*>(x);
        const int d4 = t & 31, rr = t >> 5;                        // f4 col, row phase 0..15
        const int nbeg = b * NCHUNK;
        const int nend = min(N_NODES, nbeg + NCHUNK);
        int s = nbeg;
        while (s < nend) {
            const int gseg = batch[s];
            int lo = s + 1, hi = nend;                             // find segment end
            while (lo < hi) { int m = (lo + hi) >> 1; if (batch[m] <= gseg) lo = m + 1; else hi = m; }
            const int e = lo;
            float4 a = make_float4(0.f, 0.f, 0.f, 0.f);
            for (int i = s + rr; i < e; i += 16) {
                const float4 u = x4[(size_t)i * 32 + d4];
                a.x += u.x; a.y += u.y; a.z += u.z; a.w += u.w;
            }
            __syncthreads();                                       // red free from prev iter
            red[t] = a;
            __syncthreads();
            if (t < D_NODE) {                                      // t = d4b*4 + k
                const int d4b = t >> 2, k = t & 3;
                float v2 = 0.f;
                #pragma unroll
                for (int p = 0; p < 16; ++p) {
                    const float4 u = red[p * 32 + d4b];
                    v2 += (k == 0) ? u.x : (k == 1) ? u.y : (k == 2) ? u.z : u.w;
                }
                atomicAdd(&node_agg[gseg * D_NODE + t], v2);       // ~2.3 adds per address
            }
            s = e;
        }
    }
    grid.sync();

    // ---- phase 3: place edge ids from registers into dense per-graph rows ------------
    cur[t] = pos[b * NUM_GRAPHS + t];                              // coalesced
    __syncthreads();
    #pragma unroll
    for (int r = 0; r < 6; ++r) {
        const int s = atomicAdd(&cur[gg[r]], 1);
        bucket[s] = base + r * 512 + t;                            // scattered 4B -> L2
    }
    if (grem >= 0) bucket[atomicAdd(&cur[grem], 1)] = base + 3072 + t;
}

// ---------------- kernel 2: fused edge gather-sum + tiny GEMM -------------------------
// 1024 threads -> 2 blocks/CU = 100% occupancy. Dense bucket-row id reads (L3-warm),
// 4 independent gather chains per lane; node_agg row loaded directly into feat.
__global__ __launch_bounds__(1024) void fused_kernel(const float* __restrict__ edge_attr,
                                                     const int* __restrict__ totals,
                                                     const int* __restrict__ bucket,
                                                     const float* __restrict__ node_agg,
                                                     const float* __restrict__ W,
                                                     const float* __restrict__ bias,
                                                     float* __restrict__ out) {
    const int g = blockIdx.x;
    const int t = threadIdx.x;
    __shared__ float4 red[1024];
    __shared__ float4 red2[64];
    __shared__ __align__(16) float feat[D_NODE + D_EDGE];

    const int ntot = min(totals[g], GCAP);
    const int* brow = bucket + g * GCAP;
    if (t < 32)
        reinterpret_cast<float4*>(feat)[t] =
            reinterpret_cast<const float4*>(node_agg)[g * 32 + t];   // feat[0..127]

    // edge phase: slot0 = t>>3 (0..127), dq = t&7; 4 independent id->attr gather chains
    const float4* ea4 = reinterpret_cast<const float4*>(edge_attr);
    const int slot0 = t >> 3, dq = t & 7;
    float4 a0 = make_float4(0.f, 0.f, 0.f, 0.f);
    float4 a1 = make_float4(0.f, 0.f, 0.f, 0.f);
    float4 a2 = make_float4(0.f, 0.f, 0.f, 0.f);
    float4 a3 = make_float4(0.f, 0.f, 0.f, 0.f);
    for (int base = 0; base < ntot; base += 512) {
        const int s0 = base + slot0, s1 = s0 + 128, s2 = s0 + 256, s3 = s0 + 384;
        const int id0 = (s0 < ntot) ? brow[s0] : -1;   // 8-lane broadcast, 32B/wave
        const int id1 = (s1 < ntot) ? brow[s1] : -1;
        const int id2 = (s2 < ntot) ? brow[s2] : -1;
        const int id3 = (s3 < ntot) ? brow[s3] : -1;
        if (id0 >= 0) { const float4 u = ea4[(size_t)id0 * 8 + dq]; a0.x += u.x; a0.y += u.y; a0.z += u.z; a0.w += u.w; }
        if (id1 >= 0) { const float4 u = ea4[(size_t)id1 * 8 + dq]; a1.x += u.x; a1.y += u.y; a1.z += u.z; a1.w += u.w; }
        if (id2 >= 0) { const float4 u = ea4[(size_t)id2 * 8 + dq]; a2.x += u.x; a2.y += u.y; a2.z += u.z; a2.w += u.w; }
        if (id3 >= 0) { const float4 u = ea4[(size_t)id3 * 8 + dq]; a3.x += u.x; a3.y += u.y; a3.z += u.z; a3.w += u.w; }
    }
    a0.x += a1.x + a2.x + a3.x;
    a0.y += a1.y + a2.y + a3.y;
    a0.z += a1.z + a2.z + a3.z;
    a0.w += a1.w + a2.w + a3.w;
    red[t] = a0;                                 // red[slot0*8 + dq]
    __syncthreads();
    if (t < 64) {                                // part = t>>3 (0..7), dq2 = t&7
        const int part = t >> 3, dq2 = t & 7;
        float4 s = make_float4(0.f, 0.f, 0.f, 0.f);
        #pragma unroll
        for (int k = 0; k < 16; ++k) {
            const float4 u = red[(part * 16 + k) * 8 + dq2];
            s.x += u.x; s.y += u.y; s.z += u.z; s.w += u.w;
        }
        red2[t] = s;
    }
    __syncthreads();
    if (t < 8) {
        float4 s = red2[t];
        #pragma unroll
        for (int k = 1; k < 8; ++k) {
            const float4 u = red2[k * 8 + t];
            s.x += u.x; s.y += u.y; s.z += u.z; s.w += u.w;
        }
        reinterpret_cast<float4*>(feat + D_NODE)[t] = s;   // feat[128..159]
    }
    __syncthreads();

    // gemm: out[g][t], t < 64
    if (t < D_OUT) {
        float o = bias[t];
        #pragma unroll 8
        for (int k = 0; k < D_NODE + D_EDGE; ++k)
            o += feat[k] * W[k * D_OUT + t];     // W (41 KB) L2/L3-hot, coalesced per k
        out[g * D_OUT + t] = o;
    }
}

extern "C" void kernel_launch(void* const* d_in, const int* in_sizes, int n_in,
                              void* d_out, int out_size, void* d_ws, size_t ws_size,
                              hipStream_t stream) {
    const float* x          = (const float*)d_in[0];
    const int*   edge_index = (const int*)d_in[1];
    const float* edge_attr  = (const float*)d_in[2];
    // d_in[3] = u, unused by the reference output
    const int*   batch      = (const int*)d_in[4];
    const float* W          = (const float*)d_in[5];
    const float* b          = (const float*)d_in[6];
    float* out = (float*)d_out;

    const int* col = edge_index + N_EDGES;   // row 1 of edge_index

    // workspace layout (~13 MB)
    int*   cntT     = (int*)d_ws;                                  // [g][b] 1 MB
    int*   pos      = cntT + NUM_GRAPHS * NBLK;                    // [b][g] 1 MB
    int*   totals   = pos + NBLK * NUM_GRAPHS;                     // 512 ints
    int*   bucket   = totals + NUM_GRAPHS;                         // 512*5120 = 10.5 MB
    float* node_agg = (float*)(bucket + (size_t)NUM_GRAPHS * GCAP);// 256 KB

    void* args[] = {(void*)&col, (void*)&batch, (void*)&x, (void*)&cntT,
                    (void*)&pos, (void*)&totals, (void*)&bucket, (void*)&node_agg};
    hipLaunchCooperativeKernel((const void*)prep_kernel, dim3(NBLK), dim3(512),
                               args, 0, stream);
    fused_kernel<<<NUM_GRAPHS, 1024, 0, stream>>>(edge_attr, totals, bucket,
                                                  node_agg, W, b, out);
}

// Round 13
// 89.668 us; speedup vs baseline: 2.2038x; 2.2038x over previous
//
#include <hip/hip_runtime.h>

#define NUM_GRAPHS 512
#define N_NODES 100000
#define N_EDGES 1600000
#define D_NODE 128
#define D_EDGE 32
#define D_OUT 64

#define NBLK 512                 // count/place blocks
#define EPB (N_EDGES / NBLK)     // 3125 edges per block (exact)
#define NREM (EPB - 3072)        // 53 remainder edges
#define GCAP 5120                // per-graph id cap: deg mean 3125, sigma ~228 -> 8.7 sigma
#define NCHUNK 196               // nodes per count block (512*196 >= 100000)
#define MAXSEG 3                 // segments per 196-node chunk (min graph ~146 nodes)

// ---------------- kernel 1: count + eg + node partial sums (no atomics on globals) ----
// Node streaming overlaps the latency-bound batch gathers (BW was idle in R11's count).
__global__ __launch_bounds__(512) void count_kernel(const int* __restrict__ col,
                                                    const int* __restrict__ batch,
                                                    const float* __restrict__ x,
                                                    int* __restrict__ eg,
                                                    int* __restrict__ cntT,
                                                    float* __restrict__ node_part) {
    __shared__ int cur[NUM_GRAPHS];
    __shared__ float4 red[512];
    const int t = threadIdx.x, b = blockIdx.x;
    cur[t] = 0;
    __syncthreads();
    const int base = b * EPB;

    // issue edge loads + gathers FIRST; their latency hides under the node phase
    int c[6];
    #pragma unroll
    for (int r = 0; r < 6; ++r) c[r] = col[base + r * 512 + t];
    const int crem = (t < NREM) ? col[base + 3072 + t] : 0;
    int gg[6];
    #pragma unroll
    for (int r = 0; r < 6; ++r) gg[r] = batch[c[r]];
    const int grem = (t < NREM) ? batch[crem] : -1;

    // node phase: chunk [nb, ne), <=3 segments (batch sorted), register+LDS reduction
    const int nb = b * NCHUNK, ne = min(N_NODES, nb + NCHUNK);
    const float4* x4 = reinterpret_cast<const float4*>(x);
    const int d4 = t & 31, rr = t >> 5;          // float4 col, row phase 0..15
    int s = nb, seg = 0;
    while (s < ne && seg < MAXSEG) {
        const int gseg = batch[s];
        int lo = s + 1, hi = ne;                 // segment end (uniform binary search)
        while (lo < hi) { int m = (lo + hi) >> 1; if (batch[m] <= gseg) lo = m + 1; else hi = m; }
        const int e = lo;
        float4 a = make_float4(0.f, 0.f, 0.f, 0.f);
        for (int i = s + rr; i < e; i += 16) {
            const float4 u = x4[(size_t)i * 32 + d4];
            a.x += u.x; a.y += u.y; a.z += u.z; a.w += u.w;
        }
        red[t] = a;
        __syncthreads();
        if (t < D_NODE) {                        // t = d4b*4 + k
            const int d4b = t >> 2, k = t & 3;
            float v = 0.f;
            #pragma unroll
            for (int p = 0; p < 16; ++p) {
                const float4 u = red[p * 32 + d4b];
                v += (k == 0) ? u.x : (k == 1) ? u.y : (k == 2) ? u.z : u.w;
            }
            node_part[((size_t)b * MAXSEG + seg) * D_NODE + t] = v;
        }
        __syncthreads();                         // red reused next segment
        ++seg; s = e;
    }

    // edge counting from registers
    #pragma unroll
    for (int r = 0; r < 6; ++r) {
        eg[base + r * 512 + t] = gg[r];          // coalesced
        atomicAdd(&cur[gg[r]], 1);
    }
    if (grem >= 0) {
        eg[base + 3072 + t] = grem;
        atomicAdd(&cur[grem], 1);
    }
    __syncthreads();
    cntT[t * NBLK + b] = cur[t];                 // [g][b] scattered 4B -> L2
}

// ---------------- kernel 2: per-graph scan over blocks (wave-shuffle, 1 barrier) ------
__global__ __launch_bounds__(512) void scan_kernel(const int* __restrict__ cntT,
                                                   int* __restrict__ pos,
                                                   int* __restrict__ totals) {
    const int g = blockIdx.x, t = threadIdx.x;
    const int n = cntT[g * NBLK + t];            // coalesced
    const int lane = t & 63, w = t >> 6;
    __shared__ int wtot[8], wbase[8];
    int v = n;
    #pragma unroll
    for (int off = 1; off < 64; off <<= 1) {
        const int u = __shfl_up(v, off, 64);
        if (lane >= off) v += u;
    }
    if (lane == 63) wtot[w] = v;
    __syncthreads();
    if (t == 0) {
        int s = 0;
        #pragma unroll
        for (int i = 0; i < 8; ++i) { wbase[i] = s; s += wtot[i]; }
    }
    __syncthreads();
    pos[t * NUM_GRAPHS + g] = g * GCAP + wbase[w] + v - n;   // [b][g] scattered -> L2
    if (t == 511) totals[g] = wbase[7] + v;
}

// ---------------- kernel 3: place edge ids into dense per-graph rows ------------------
__global__ __launch_bounds__(512) void place_kernel(const int* __restrict__ eg,
                                                    const int* __restrict__ pos,
                                                    int* __restrict__ bucket) {
    __shared__ int cur[NUM_GRAPHS];
    const int t = threadIdx.x, b = blockIdx.x;
    cur[t] = pos[b * NUM_GRAPHS + t];            // coalesced
    __syncthreads();
    const int base = b * EPB;
    #pragma unroll
    for (int r = 0; r < 6; ++r) {
        const int i = r * 512 + t;
        const int g = eg[base + i];              // coalesced
        const int s = atomicAdd(&cur[g], 1);
        bucket[s] = base + i;                    // scattered 4B -> L2 (10.5 MB fits)
    }
    if (t < NREM) {
        const int i = 3072 + t;
        const int g = eg[base + i];
        bucket[atomicAdd(&cur[g], 1)] = base + i;
    }
}

// ---------------- kernel 4: fused edge gather-sum (8 chains) + node collect + GEMM ----
__global__ __launch_bounds__(1024) void fused_kernel(const float* __restrict__ edge_attr,
                                                     const int* __restrict__ batch,
                                                     const int* __restrict__ totals,
                                                     const int* __restrict__ bucket,
                                                     const float* __restrict__ node_part,
                                                     const float* __restrict__ W,
                                                     const float* __restrict__ bias,
                                                     float* __restrict__ out) {
    const int g = blockIdx.x;
    const int t = threadIdx.x;
    __shared__ float4 red[1024];
    __shared__ float4 red2[64];
    __shared__ __align__(16) float feat[D_NODE + D_EDGE];

    const int ntot = min(totals[g], GCAP);
    const int* brow = bucket + g * GCAP;

    // node collect: sum <=3 staged partial rows (chunks overlapping graph g's node range)
    int l = 0, r = N_NODES;
    while (l < r) { int m = (l + r) >> 1; if (batch[m] < g) l = m + 1; else r = m; }
    const int lo = l;
    r = N_NODES;
    while (l < r) { int m = (l + r) >> 1; if (batch[m] < g + 1) l = m + 1; else r = m; }
    const int hi = l;
    if (t < D_NODE) {
        float nv = 0.f;
        if (lo < hi) {
            const int cb0 = lo / NCHUNK, cb1 = (hi - 1) / NCHUNK;
            for (int cb = cb0; cb <= cb1; ++cb) {
                const int sg = g - batch[cb * NCHUNK];   // segment rank within chunk
                if (sg >= 0 && sg < MAXSEG)
                    nv += node_part[((size_t)cb * MAXSEG + sg) * D_NODE + t];
            }
        }
        feat[t] = nv;
    }

    // edge phase: slot0 = t>>3 (0..127), dq = t&7; 8 independent gather chains
    const float4* ea4 = reinterpret_cast<const float4*>(edge_attr);
    const int slot0 = t >> 3, dq = t & 7;
    float4 acc0 = make_float4(0.f,0.f,0.f,0.f), acc1 = acc0, acc2 = acc0, acc3 = acc0;
    float4 acc4 = acc0, acc5 = acc0, acc6 = acc0, acc7 = acc0;
    for (int base = 0; base < ntot; base += 1024) {
        int id[8];
        #pragma unroll
        for (int k = 0; k < 8; ++k) {
            const int s = base + slot0 + k * 128;
            id[k] = (s < ntot) ? brow[s] : -1;   // 8-lane broadcast, L2/L3-warm
        }
        #pragma unroll
        for (int k = 0; k < 8; ++k) {
            if (id[k] >= 0) {
                const float4 u = ea4[(size_t)id[k] * 8 + dq];
                if (k == 0) { acc0.x+=u.x; acc0.y+=u.y; acc0.z+=u.z; acc0.w+=u.w; }
                if (k == 1) { acc1.x+=u.x; acc1.y+=u.y; acc1.z+=u.z; acc1.w+=u.w; }
                if (k == 2) { acc2.x+=u.x; acc2.y+=u.y; acc2.z+=u.z; acc2.w+=u.w; }
                if (k == 3) { acc3.x+=u.x; acc3.y+=u.y; acc3.z+=u.z; acc3.w+=u.w; }
                if (k == 4) { acc4.x+=u.x; acc4.y+=u.y; acc4.z+=u.z; acc4.w+=u.w; }
                if (k == 5) { acc5.x+=u.x; acc5.y+=u.y; acc5.z+=u.z; acc5.w+=u.w; }
                if (k == 6) { acc6.x+=u.x; acc6.y+=u.y; acc6.z+=u.z; acc6.w+=u.w; }
                if (k == 7) { acc7.x+=u.x; acc7.y+=u.y; acc7.z+=u.z; acc7.w+=u.w; }
            }
        }
    }
    acc0.x += acc1.x + acc2.x + acc3.x + acc4.x + acc5.x + acc6.x + acc7.x;
    acc0.y += acc1.y + acc2.y + acc3.y + acc4.y + acc5.y + acc6.y + acc7.y;
    acc0.z += acc1.z + acc2.z + acc3.z + acc4.z + acc5.z + acc6.z + acc7.z;
    acc0.w += acc1.w + acc2.w + acc3.w + acc4.w + acc5.w + acc6.w + acc7.w;
    red[t] = acc0;                               // red[slot0*8 + dq]
    __syncthreads();
    if (t < 64) {                                // part = t>>3 (0..7), dq2 = t&7
        const int part = t >> 3, dq2 = t & 7;
        float4 s = make_float4(0.f, 0.f, 0.f, 0.f);
        #pragma unroll
        for (int k = 0; k < 16; ++k) {
            const float4 u = red[(part * 16 + k) * 8 + dq2];
            s.x += u.x; s.y += u.y; s.z += u.z; s.w += u.w;
        }
        red2[t] = s;
    }
    __syncthreads();
    if (t < 8) {
        float4 s = red2[t];
        #pragma unroll
        for (int k = 1; k < 8; ++k) {
            const float4 u = red2[k * 8 + t];
            s.x += u.x; s.y += u.y; s.z += u.z; s.w += u.w;
        }
        reinterpret_cast<float4*>(feat + D_NODE)[t] = s;   // feat[128..159]
    }
    __syncthreads();

    // gemm: out[g][t], t < 64
    if (t < D_OUT) {
        float o = bias[t];
        #pragma unroll 8
        for (int k = 0; k < D_NODE + D_EDGE; ++k)
            o += feat[k] * W[k * D_OUT + t];     // W (41 KB) L2/L3-hot, coalesced per k
        out[g * D_OUT + t] = o;
    }
}

extern "C" void kernel_launch(void* const* d_in, const int* in_sizes, int n_in,
                              void* d_out, int out_size, void* d_ws, size_t ws_size,
                              hipStream_t stream) {
    const float* x          = (const float*)d_in[0];
    const int*   edge_index = (const int*)d_in[1];
    const float* edge_attr  = (const float*)d_in[2];
    // d_in[3] = u, unused by the reference output
    const int*   batch      = (const int*)d_in[4];
    const float* W          = (const float*)d_in[5];
    const float* b          = (const float*)d_in[6];
    float* out = (float*)d_out;

    const int* col = edge_index + N_EDGES;   // row 1 of edge_index

    // workspace layout (~19.7 MB)
    int*   eg        = (int*)d_ws;                                 // 6.4 MB
    int*   cntT      = eg + N_EDGES;                               // [g][b] 1 MB
    int*   pos       = cntT + NUM_GRAPHS * NBLK;                   // [b][g] 1 MB
    int*   totals    = pos + NBLK * NUM_GRAPHS;                    // 512 ints
    int*   bucket    = totals + NUM_GRAPHS;                        // 10.5 MB
    float* node_part = (float*)(bucket + (size_t)NUM_GRAPHS * GCAP); // 512*3*128 f = 786 KB

    count_kernel<<<NBLK, 512, 0, stream>>>(col, batch, x, eg, cntT, node_part);
    scan_kernel<<<NUM_GRAPHS, 512, 0, stream>>>(cntT, pos, totals);
    place_kernel<<<NBLK, 512, 0, stream>>>(eg, pos, bucket);
    fused_kernel<<<NUM_GRAPHS, 1024, 0, stream>>>(edge_attr, batch, totals, bucket,
                                                  node_part, W, b, out);
}

// Round 15
// 85.007 us; speedup vs baseline: 2.3247x; 1.0548x over previous
//
#include <hip/hip_runtime.h>

#define NUM_GRAPHS 512
#define N_NODES 100000
#define N_EDGES 1600000
#define D_NODE 128
#define D_EDGE 32
#define D_OUT 64

#define NBLK 512                 // count/place blocks
#define EPB (N_EDGES / NBLK)     // 3125 edges per block (exact)
#define NREM (EPB - 3072)        // 53 remainder edges
#define GCAP 5120                // per-graph id cap: deg mean 3125, sigma ~228 -> 8.7 sigma

typedef float nfloat4 __attribute__((ext_vector_type(4)));   // native vector for NT builtin

__device__ inline float4 ntload4(const float4* p) {
    nfloat4 v = __builtin_nontemporal_load(reinterpret_cast<const nfloat4*>(p));
    return make_float4(v.x, v.y, v.z, v.w);      // single-use stream: skip cache allocation
}

// ---------------- kernel 1: count per-(block,graph) + materialize eg ------------------
__global__ __launch_bounds__(512) void count_kernel(const int* __restrict__ col,
                                                    const int* __restrict__ batch,
                                                    int* __restrict__ eg,
                                                    int* __restrict__ cntT) {
    __shared__ int cur[NUM_GRAPHS];
    const int t = threadIdx.x, b = blockIdx.x;
    cur[t] = 0;
    __syncthreads();
    const int base = b * EPB;

    int c[6], gg[6];
    #pragma unroll
    for (int r = 0; r < 6; ++r) c[r] = col[base + r * 512 + t];      // 6 coalesced loads in flight
    #pragma unroll
    for (int r = 0; r < 6; ++r) gg[r] = batch[c[r]];                 // 6 independent gathers
    #pragma unroll
    for (int r = 0; r < 6; ++r) {
        eg[base + r * 512 + t] = gg[r];                              // coalesced
        atomicAdd(&cur[gg[r]], 1);
    }
    if (t < NREM) {                                                  // 53 remainder
        const int g = batch[col[base + 3072 + t]];
        eg[base + 3072 + t] = g;
        atomicAdd(&cur[g], 1);
    }
    __syncthreads();
    cntT[t * NBLK + b] = cur[t];                                     // [g][b], scattered -> L2
}

// ---------------- kernel 2: per-graph scan over blocks (wave-shuffle, 1 barrier) ------
__global__ __launch_bounds__(512) void scan_kernel(const int* __restrict__ cntT,
                                                   int* __restrict__ pos,
                                                   int* __restrict__ totals) {
    const int g = blockIdx.x, t = threadIdx.x;
    const int n = cntT[g * NBLK + t];                                // coalesced
    const int lane = t & 63, w = t >> 6;
    __shared__ int wtot[8], wbase[8];
    int v = n;
    #pragma unroll
    for (int off = 1; off < 64; off <<= 1) {
        const int u = __shfl_up(v, off, 64);
        if (lane >= off) v += u;
    }
    if (lane == 63) wtot[w] = v;
    __syncthreads();
    if (t == 0) {
        int s = 0;
        #pragma unroll
        for (int i = 0; i < 8; ++i) { wbase[i] = s; s += wtot[i]; }
    }
    __syncthreads();
    pos[t * NUM_GRAPHS + g] = g * GCAP + wbase[w] + v - n;           // [b][g], scattered -> L2
    if (t == 511) totals[g] = wbase[7] + v;
}

// ---------------- kernel 3: place edge ids into dense per-graph rows ------------------
__global__ __launch_bounds__(512) void place_kernel(const int* __restrict__ eg,
                                                    const int* __restrict__ pos,
                                                    int* __restrict__ bucket) {
    __shared__ int cur[NUM_GRAPHS];
    const int t = threadIdx.x, b = blockIdx.x;
    cur[t] = pos[b * NUM_GRAPHS + t];                                // coalesced
    __syncthreads();
    const int base = b * EPB;
    #pragma unroll
    for (int r = 0; r < 6; ++r) {
        const int i = r * 512 + t;
        const int g = eg[base + i];                                  // coalesced
        const int s = atomicAdd(&cur[g], 1);
        bucket[s] = base + i;                                        // scattered 4B -> L2 (10.5MB fits)
    }
    if (t < NREM) {
        const int i = 3072 + t;
        const int g = eg[base + i];
        bucket[atomicAdd(&cur[g], 1)] = base + i;
    }
}

// ---------------- kernel 4: fused node-sum + edge gather-sum + tiny GEMM --------------
// 1024 threads -> 2 blocks/CU (32 waves/CU). Dense id row staged to LDS first (coalesced,
// overlaps node phase) so the gather loop has NO global id dependency; NT loads on the
// two single-use streams (x, edge_attr).
__global__ __launch_bounds__(1024) void fused_kernel(const float* __restrict__ x,
                                                     const int* __restrict__ batch,
                                                     const float* __restrict__ edge_attr,
                                                     const int* __restrict__ totals,
                                                     const int* __restrict__ bucket,
                                                     const float* __restrict__ W,
                                                     const float* __restrict__ bias,
                                                     float* __restrict__ out) {
    const int g = blockIdx.x;
    const int t = threadIdx.x;
    __shared__ int ids[GCAP];                    // 20 KB
    __shared__ float4 red[1024];                 // 16 KB (node partials, then edge partials)
    __shared__ float4 red2[64];
    __shared__ __align__(16) float feat[D_NODE + D_EDGE];

    const int ntot = min(totals[g], GCAP);
    const int* brow = bucket + g * GCAP;
    // stage ids to LDS first; these coalesced loads drain under the node phase
    for (int i = t; i < ntot; i += 1024) ids[i] = brow[i];

    // node range via binary search (batch sorted)
    int l = 0, r = N_NODES;
    while (l < r) { int m = (l + r) >> 1; if (batch[m] < g) l = m + 1; else r = m; }
    const int lo = l;
    r = N_NODES;
    while (l < r) { int m = (l + r) >> 1; if (batch[m] < g + 1) l = m + 1; else r = m; }
    const int hi = l;

    // node phase: d4 = t&31 float4 col, rr = t>>5 row phase (0..31)
    const float4* x4 = reinterpret_cast<const float4*>(x);
    const int d4 = t & 31, rr = t >> 5;
    float4 a = make_float4(0.f, 0.f, 0.f, 0.f);
    for (int i = lo + rr; i < hi; i += 32) {
        const float4 v = ntload4(&x4[(size_t)i * 32 + d4]);
        a.x += v.x; a.y += v.y; a.z += v.z; a.w += v.w;
    }
    red[t] = a;
    __syncthreads();                             // covers red[] AND ids[]
    if (t < 32) {                                // node reduce -> feat[0..127]
        float4 s = red[t];
        #pragma unroll
        for (int p = 1; p < 32; ++p) {
            const float4 u = red[p * 32 + t];
            s.x += u.x; s.y += u.y; s.z += u.z; s.w += u.w;
        }
        reinterpret_cast<float4*>(feat)[t] = s;
    }
    __syncthreads();                             // red free for reuse

    // edge phase: slot0 = t>>3 (0..127), dq = t&7; 4 gather chains, ids from LDS
    const float4* ea4 = reinterpret_cast<const float4*>(edge_attr);
    const int slot0 = t >> 3, dq = t & 7;
    float4 a0 = make_float4(0.f, 0.f, 0.f, 0.f);
    float4 a1 = make_float4(0.f, 0.f, 0.f, 0.f);
    float4 a2 = make_float4(0.f, 0.f, 0.f, 0.f);
    float4 a3 = make_float4(0.f, 0.f, 0.f, 0.f);
    for (int base = 0; base < ntot; base += 512) {
        const int s0 = base + slot0, s1 = s0 + 128, s2 = s0 + 256, s3 = s0 + 384;
        const int id0 = (s0 < ntot) ? ids[s0] : -1;    // LDS read: ~0 latency, no global dep
        const int id1 = (s1 < ntot) ? ids[s1] : -1;
        const int id2 = (s2 < ntot) ? ids[s2] : -1;
        const int id3 = (s3 < ntot) ? ids[s3] : -1;
        if (id0 >= 0) { const float4 u = ntload4(&ea4[(size_t)id0 * 8 + dq]); a0.x += u.x; a0.y += u.y; a0.z += u.z; a0.w += u.w; }
        if (id1 >= 0) { const float4 u = ntload4(&ea4[(size_t)id1 * 8 + dq]); a1.x += u.x; a1.y += u.y; a1.z += u.z; a1.w += u.w; }
        if (id2 >= 0) { const float4 u = ntload4(&ea4[(size_t)id2 * 8 + dq]); a2.x += u.x; a2.y += u.y; a2.z += u.z; a2.w += u.w; }
        if (id3 >= 0) { const float4 u = ntload4(&ea4[(size_t)id3 * 8 + dq]); a3.x += u.x; a3.y += u.y; a3.z += u.z; a3.w += u.w; }
    }
    a0.x += a1.x + a2.x + a3.x;
    a0.y += a1.y + a2.y + a3.y;
    a0.z += a1.z + a2.z + a3.z;
    a0.w += a1.w + a2.w + a3.w;
    red[t] = a0;                                 // red[slot0*8 + dq]
    __syncthreads();
    if (t < 64) {                                // part = t>>3 (0..7), dq2 = t&7
        const int part = t >> 3, dq2 = t & 7;
        float4 s = make_float4(0.f, 0.f, 0.f, 0.f);
        #pragma unroll
        for (int k = 0; k < 16; ++k) {
            const float4 u = red[(part * 16 + k) * 8 + dq2];
            s.x += u.x; s.y += u.y; s.z += u.z; s.w += u.w;
        }
        red2[t] = s;
    }
    __syncthreads();
    if (t < 8) {
        float4 s = red2[t];
        #pragma unroll
        for (int k = 1; k < 8; ++k) {
            const float4 u = red2[k * 8 + t];
            s.x += u.x; s.y += u.y; s.z += u.z; s.w += u.w;
        }
        reinterpret_cast<float4*>(feat + D_NODE)[t] = s;   // feat[128..159]
    }
    __syncthreads();

    // gemm: out[g][t], t < 64
    if (t < D_OUT) {
        float o = bias[t];
        #pragma unroll 8
        for (int k = 0; k < D_NODE + D_EDGE; ++k)
            o += feat[k] * W[k * D_OUT + t];     // W (41 KB) L2/L3-hot, coalesced per k
        out[g * D_OUT + t] = o;
    }
}

extern "C" void kernel_launch(void* const* d_in, const int* in_sizes, int n_in,
                              void* d_out, int out_size, void* d_ws, size_t ws_size,
                              hipStream_t stream) {
    const float* x          = (const float*)d_in[0];
    const int*   edge_index = (const int*)d_in[1];
    const float* edge_attr  = (const float*)d_in[2];
    // d_in[3] = u, unused by the reference output
    const int*   batch      = (const int*)d_in[4];
    const float* W          = (const float*)d_in[5];
    const float* b          = (const float*)d_in[6];
    float* out = (float*)d_out;

    const int* col = edge_index + N_EDGES;   // row 1 of edge_index

    // workspace layout (~18.9 MB)
    int* eg     = (int*)d_ws;                                  // 6.4 MB
    int* cntT   = eg + N_EDGES;                                // [g][b] 1 MB
    int* pos    = cntT + NUM_GRAPHS * NBLK;                    // [b][g] 1 MB
    int* totals = pos + NBLK * NUM_GRAPHS;                     // 512 ints
    int* bucket = totals + NUM_GRAPHS;                         // 512*5120 = 10.5 MB

    count_kernel<<<NBLK, 512, 0, stream>>>(col, batch, eg, cntT);
    scan_kernel<<<NUM_GRAPHS, 512, 0, stream>>>(cntT, pos, totals);
    place_kernel<<<NBLK, 512, 0, stream>>>(eg, pos, bucket);
    fused_kernel<<<NUM_GRAPHS, 1024, 0, stream>>>(x, batch, edge_attr, totals, bucket, W, b, out);
}